// Round 4
// baseline (129.289 us; speedup 1.0000x reference)
//
#include <hip/hip_runtime.h>
#include <hip/hip_bf16.h>
#include <math.h>

// ---------------------------------------------------------------------------
// Problem constants (from setup_inputs)
#define NPIX   589824      // 768*768
#define NEIK   100000
#define NSDF   100000
#define PP     50000
#define SPTS   8192        // points per cloud

// k_main regions (256 thr / block)
#define B_CHAM 512         // 2 dirs x 8 src-chunks(1024) x 32 dst-chunks(256)
#define B_PIX  576         // 576*256 threads, 4 pixels each = NPIX
#define B_EIK  98          // 4 points/thread, guard at 25000 groups
#define B_SDF  98
#define B_CON  196         // 1 point/thread, guard 50000
#define B_MAIN (B_CHAM + B_PIX + B_EIK + B_SDF + B_CON)   // 1480
// k_mid regions
#define B_DEP  576         // depth pass 2: 4 pixels/thread
#define B_PC   64          // chamfer partial-min reduce: 64*256 = 16384 sources
#define B_MID  (B_DEP + B_PC)

// ---------------------------------------------------------------------------
// ws layout (32-bit words). ALL outputs are plain stores into disjoint slots:
// no atomics anywhere, no initialization required (every read slot is written
// exactly once by an earlier kernel in the same call).
#define OFF_MASK  0        // 2304 wave partials (576 blocks x 4 waves)
#define OFF_NERR  2304
#define OFF_DEN   4608
#define OFF_NUM   6912
#define OFF_BCE   9216
#define OFF_EIK   11520    // 392
#define OFF_SDF   11912    // 392
#define OFF_CON   12304    // 784
#define OFF_VIS   13088    // 784
#define OFF_DEP   13872    // 2304
#define OFF_PC    16176    // 256
#define OFF_CHAM  16640    // 32 chunk-partials x 16384 sources = 524288 words

__device__ __forceinline__ float nan0(float x) { return isfinite(x) ? x : 0.0f; }

__device__ __forceinline__ float waveReduce(float v) {
    v += __shfl_down(v, 32); v += __shfl_down(v, 16); v += __shfl_down(v, 8);
    v += __shfl_down(v, 4);  v += __shfl_down(v, 2);  v += __shfl_down(v, 1);
    return v;
}

// valid on thread 0 only; block must be 256 threads (4 waves)
__device__ __forceinline__ float blockReduce(float v, float* sbuf) {
    v = waveReduce(v);
    int lane = threadIdx.x & 63, w = threadIdx.x >> 6;
    __syncthreads();                  // protect sbuf across back-to-back calls
    if (lane == 0) sbuf[w] = v;
    __syncthreads();
    float r = 0.0f;
    if (threadIdx.x == 0) r = sbuf[0] + sbuf[1] + sbuf[2] + sbuf[3];
    return r;
}

__device__ __forceinline__ float blockSumArr(const float* a, int n, float* sbuf) {
    float s = 0;
    for (int i = threadIdx.x; i < n; i += 256) s += a[i];
    return blockReduce(s, sbuf);      // thread 0 only
}

union F12 { float4 v[3]; float f[12]; };

// ---------------------------------------------------------------------------
__global__ __launch_bounds__(256) void k_main(
    const float* __restrict__ normal_pred, const float* __restrict__ normal_gt,
    const float* __restrict__ depth_pred,  const float* __restrict__ depth_gt,
    const float* __restrict__ X,           const float* __restrict__ Y,
    const float* __restrict__ mask,        const float* __restrict__ comp_mask,
    const float* __restrict__ gradients,   const float* __restrict__ sdf,
    const float* __restrict__ nwa,         const float* __restrict__ vm,
    const float* __restrict__ wts,         float* __restrict__ ws)
{
    int b = blockIdx.x, t = threadIdx.x;
    int lane = t & 63, w = t >> 6;
    if (b < B_CHAM) {
        // ---- chamfer partials: rank r = 0.5|y|^2 - x.y (3 FMA + 1 min/pair);
        // partial-min + 0.5|x|^2 = min d2/2 over this dst chunk, plain store.
        int dir = b >> 8;            // 0: X->Y, 1: Y->X
        int r   = b & 255;
        int sc  = r >> 5;            // src chunk 0..7 (1024 sources)
        int dc  = r & 31;            // dst chunk 0..31 (256 dests)
        const float* src = dir ? Y : X;
        const float* dst = dir ? X : Y;
        __shared__ float4 ybuf[256];
        {
            int d = dc * 256 + t;
            float y0 = dst[3*d], y1 = dst[3*d+1], y2 = dst[3*d+2];
            ybuf[t] = make_float4(y0, y1, y2, 0.5f * (y0*y0 + y1*y1 + y2*y2));
        }
        float nx0[4], nx1[4], nx2[4], hx2[4], mn[4];
#pragma unroll
        for (int j = 0; j < 4; ++j) {
            int s = sc * 1024 + t + j * 256;
            float x0 = src[3*s], x1 = src[3*s+1], x2 = src[3*s+2];
            nx0[j] = -x0; nx1[j] = -x1; nx2[j] = -x2;
            hx2[j] = 0.5f * (x0*x0 + x1*x1 + x2*x2);
            mn[j]  = 1e30f;
        }
        __syncthreads();
#pragma unroll 4
        for (int dd = 0; dd < 256; ++dd) {
            float4 y = ybuf[dd];     // uniform address -> LDS broadcast
#pragma unroll
            for (int j = 0; j < 4; ++j) {
                float rr = fmaf(nx0[j], y.x, y.w);
                rr = fmaf(nx1[j], y.y, rr);
                rr = fmaf(nx2[j], y.z, rr);
                mn[j] = fminf(mn[j], rr);
            }
        }
        int base = OFF_CHAM + dc * 16384 + dir * 8192 + sc * 1024 + t;
#pragma unroll
        for (int j = 0; j < 4; ++j)
            ws[base + j * 256] = mn[j] + hx2[j];   // coalesced plain store
    } else if (b < B_CHAM + B_PIX) {
        int pb = b - B_CHAM;
        int g = pb * 256 + t;                      // pixel group, 4 pixels
        float4 m4  = ((const float4*)mask)[g];
        float4 c4  = ((const float4*)comp_mask)[g];
        float4 dg4 = ((const float4*)depth_gt)[g];
        float4 dp4 = ((const float4*)depth_pred)[g];
        F12 np, ng;
        np.v[0] = ((const float4*)normal_pred)[3*g];
        np.v[1] = ((const float4*)normal_pred)[3*g+1];
        np.v[2] = ((const float4*)normal_pred)[3*g+2];
        ng.v[0] = ((const float4*)normal_gt)[3*g];
        ng.v[1] = ((const float4*)normal_gt)[3*g+1];
        ng.v[2] = ((const float4*)normal_gt)[3*g+2];
        float mm[4] = { m4.x, m4.y, m4.z, m4.w };
        float cc[4] = { c4.x, c4.y, c4.z, c4.w };
        float gg[4] = { dg4.x, dg4.y, dg4.z, dg4.w };
        float pp[4] = { dp4.x, dp4.y, dp4.z, dp4.w };
        float s_mask = 0, s_nerr = 0, s_den = 0, s_num = 0, s_bce = 0;
#pragma unroll
        for (int k = 0; k < 4; ++k) {
            float m = mm[k] > 0.5f ? 1.0f : 0.0f;
            s_mask += m;
            float e0 = nan0(np.f[3*k])   - nan0(ng.f[3*k]);
            float e1 = nan0(np.f[3*k+1]) - nan0(ng.f[3*k+1]);
            float e2 = nan0(np.f[3*k+2]) - nan0(ng.f[3*k+2]);
            s_nerr += m * (e0*e0 + e1*e1 + e2*e2);
            float vg = (m == 1.0f) ? nan0(gg[k]) : 0.0f;
            float vp = (m == 1.0f) ? nan0(pp[k]) : 0.0f;
            s_den += vg * vg;
            s_num += vg * vp;
            float c = cc[k];
            c = fminf(fmaxf(c, 0.0f), 1.0f);       // clip; +inf->1, -inf->0
            if (isnan(c)) c = 0.5f;                // nan->0.5
            c = fminf(fmaxf(c, 1e-5f), 1.0f - 1e-5f);
            s_bce -= m * __logf(c) + (1.0f - m) * __logf(1.0f - c);
        }
        s_mask = waveReduce(s_mask); s_nerr = waveReduce(s_nerr);
        s_den  = waveReduce(s_den);  s_num  = waveReduce(s_num);
        s_bce  = waveReduce(s_bce);
        if (lane == 0) {
            int idx = pb * 4 + w;                  // per-wave partial slot
            ws[OFF_MASK + idx] = s_mask;
            ws[OFF_NERR + idx] = s_nerr;
            ws[OFF_DEN  + idx] = s_den;
            ws[OFF_NUM  + idx] = s_num;
            ws[OFF_BCE  + idx] = s_bce;
        }
    } else if (b < B_CHAM + B_PIX + B_EIK) {
        int eb = b - (B_CHAM + B_PIX);
        int i = eb * 256 + t;                      // group of 4 points
        float acc = 0;
        if (i < NEIK / 4) {
            F12 gr;
            gr.v[0] = ((const float4*)gradients)[3*i];
            gr.v[1] = ((const float4*)gradients)[3*i+1];
            gr.v[2] = ((const float4*)gradients)[3*i+2];
#pragma unroll
            for (int k = 0; k < 4; ++k) {
                float g0 = gr.f[3*k], g1 = gr.f[3*k+1], g2 = gr.f[3*k+2];
                float n = sqrtf(g0*g0 + g1*g1 + g2*g2) - 1.0f;
                acc += n * n;
            }
        }
        acc = waveReduce(acc);
        if (lane == 0) ws[OFF_EIK + eb * 4 + w] = acc;
    } else if (b < B_CHAM + B_PIX + B_EIK + B_SDF) {
        int sb = b - (B_CHAM + B_PIX + B_EIK);
        int i = sb * 256 + t;                      // group of 4
        float acc = 0;
        if (i < NSDF / 4) {
            float4 s4 = ((const float4*)sdf)[i];
            acc = fabsf(s4.x) + fabsf(s4.y) + fabsf(s4.z) + fabsf(s4.w);
        }
        acc = waveReduce(acc);
        if (lane == 0) ws[OFF_SDF + sb * 4 + w] = acc;
    } else {
        int cb = b - (B_CHAM + B_PIX + B_EIK + B_SDF);
        int p = cb * 256 + t;                      // one point, 3 cam pairs
        float s_con = 0, s_vis = 0;
        if (p < PP) {
            F12 a;
            a.v[0] = ((const float4*)nwa)[3*p];
            a.v[1] = ((const float4*)nwa)[3*p+1];
            a.v[2] = ((const float4*)nwa)[3*p+2];
            float4 v4 = ((const float4*)vm)[p];
            float vv[4] = { v4.x, v4.y, v4.z, v4.w };
            float wt = wts[p];
#pragma unroll
            for (int pr = 0; pr < 3; ++pr) {
                float d0 = a.f[3*pr]   - a.f[3*pr+3];
                float d1 = a.f[3*pr+1] - a.f[3*pr+4];
                float d2 = a.f[3*pr+2] - a.f[3*pr+5];
                float mse = d0*d0 + d1*d1 + d2*d2;
                float vis = vv[pr] * vv[pr+1];
                s_vis += vis;
                s_con += mse * vis * wt;
            }
        }
        s_con = waveReduce(s_con); s_vis = waveReduce(s_vis);
        if (lane == 0) {
            ws[OFF_CON + cb * 4 + w] = s_con;
            ws[OFF_VIS + cb * 4 + w] = s_vis;
        }
    }
}

// ---------------------------------------------------------------------------
// depth pass 2 (scale recomputed per block from den/num wave partials) +
// chamfer partial-min reduction.
__global__ __launch_bounds__(256) void k_mid(
    const float* __restrict__ depth_pred, const float* __restrict__ depth_gt,
    const float* __restrict__ mask, float* __restrict__ ws)
{
    int b = blockIdx.x, t = threadIdx.x;
    int lane = t & 63, w = t >> 6;
    if (b < B_DEP) {
        __shared__ float sh[8];
        __shared__ float sscale;
        float pd = 0, pn = 0;
        for (int i = t; i < 2304; i += 256) {
            pd += ws[OFF_DEN + i];
            pn += ws[OFF_NUM + i];
        }
        pd = waveReduce(pd); pn = waveReduce(pn);
        if (lane == 0) { sh[w] = pd; sh[4 + w] = pn; }
        __syncthreads();
        if (t == 0) {
            float den = sh[0] + sh[1] + sh[2] + sh[3];
            float num = sh[4] + sh[5] + sh[6] + sh[7];
            float sc = num / den;
            if (!isfinite(sc)) sc = 1.0f;          // nan_to_num(nan=1, +-inf=1)
            sscale = sc;
        }
        __syncthreads();
        float scale = sscale;
        int g = b * 256 + t;                       // 4 pixels per thread
        float4 m4  = ((const float4*)mask)[g];
        float4 dg4 = ((const float4*)depth_gt)[g];
        float4 dp4 = ((const float4*)depth_pred)[g];
        float mm[4] = { m4.x, m4.y, m4.z, m4.w };
        float gg[4] = { dg4.x, dg4.y, dg4.z, dg4.w };
        float pp[4] = { dp4.x, dp4.y, dp4.z, dp4.w };
        float acc = 0;
#pragma unroll
        for (int k = 0; k < 4; ++k) {
            float m  = mm[k] > 0.5f ? 1.0f : 0.0f;
            float vg = (m == 1.0f) ? nan0(gg[k]) : 0.0f;
            float vp = (m == 1.0f) ? nan0(pp[k]) : 0.0f;
            acc += fabsf(vg * scale - vp);
        }
        acc = waveReduce(acc);
        if (lane == 0) ws[OFF_DEP + b * 4 + w] = acc;
    } else {
        int rb = b - B_DEP;
        int g = rb * 256 + t;                      // source id, 0..16383
        float mn = 1e30f;
#pragma unroll 8
        for (int dc = 0; dc < 32; ++dc)
            mn = fminf(mn, ws[OFF_CHAM + dc * 16384 + g]);  // coalesced
        float v = sqrtf(fmaxf(2.0f * mn, 0.0f));   // sqrt(d2_min)
        v = waveReduce(v);
        if (lane == 0) ws[OFF_PC + rb * 4 + w] = v;
    }
}

// ---------------------------------------------------------------------------
// single block: sum all wave partials, assemble the loss.
__global__ __launch_bounds__(256) void k_finalize(
    const float* __restrict__ ws, float* __restrict__ out)
{
    __shared__ float sbuf[4];
    int t = threadIdx.x;
    float mask_s = blockSumArr(ws + OFF_MASK, 2304, sbuf);
    float nerr   = blockSumArr(ws + OFF_NERR, 2304, sbuf);
    float den    = blockSumArr(ws + OFF_DEN,  2304, sbuf);
    float bce    = blockSumArr(ws + OFF_BCE,  2304, sbuf);
    float eik    = blockSumArr(ws + OFF_EIK,  392,  sbuf);
    float sdfs   = blockSumArr(ws + OFF_SDF,  392,  sbuf);
    float con    = blockSumArr(ws + OFF_CON,  784,  sbuf);
    float vis    = blockSumArr(ws + OFF_VIS,  784,  sbuf);
    float dep    = blockSumArr(ws + OFF_DEP,  2304, sbuf);
    float pc     = blockSumArr(ws + OFF_PC,   256,  sbuf);
    if (t == 0) {
        float mask_sum = mask_s + 1e-5f;
        float normal_loss = nerr / mask_sum;
        float depth_loss = dep / (mask_sum + 1e-8f);
        if (den < 1e-10f) depth_loss = 0.0f;
        depth_loss = nan0(depth_loss);
        float pc_loss  = pc / (float)SPTS;         // both dirs share /8192
        float bce_l    = bce / (float)NPIX;
        float eik_l    = eik / (float)NEIK;
        float sdf_l    = sdfs / (float)NSDF;
        float con_l    = vis > 0.0f ? con / vis : 0.0f;
        out[0] = normal_loss + depth_loss + pc_loss + bce_l + eik_l + sdf_l + con_l;
    }
}

// ---------------------------------------------------------------------------
extern "C" void kernel_launch(void* const* d_in, const int* in_sizes, int n_in,
                              void* d_out, int out_size, void* d_ws, size_t ws_size,
                              hipStream_t stream) {
    const float* normal_pred = (const float*)d_in[0];
    const float* normal_gt   = (const float*)d_in[1];
    const float* depth_pred  = (const float*)d_in[2];
    const float* depth_gt    = (const float*)d_in[3];
    const float* X           = (const float*)d_in[4];
    const float* Y           = (const float*)d_in[5];
    const float* mask        = (const float*)d_in[6];
    const float* comp_mask   = (const float*)d_in[7];
    const float* gradients   = (const float*)d_in[8];
    const float* sdf         = (const float*)d_in[9];
    const float* nwa         = (const float*)d_in[10];
    const float* vm          = (const float*)d_in[11];
    const float* wts         = (const float*)d_in[12];
    float* ws  = (float*)d_ws;
    float* out = (float*)d_out;

    k_main<<<dim3(B_MAIN), dim3(256), 0, stream>>>(
        normal_pred, normal_gt, depth_pred, depth_gt, X, Y, mask, comp_mask,
        gradients, sdf, nwa, vm, wts, ws);
    k_mid<<<dim3(B_MID), dim3(256), 0, stream>>>(depth_pred, depth_gt, mask, ws);
    k_finalize<<<dim3(1), dim3(256), 0, stream>>>(ws, out);
}